// Round 9
// baseline (475.702 us; speedup 1.0000x reference)
//
#include <hip/hip_runtime.h>

typedef __attribute__((ext_vector_type(8))) __bf16 bf16x8;
typedef __attribute__((ext_vector_type(4))) float f32x4;

__device__ __forceinline__ ushort f2bf(float f) {
  union { float f; unsigned u; } x; x.f = f;
  unsigned r = x.u + 0x7FFFu + ((x.u >> 16) & 1u);
  return (ushort)(r >> 16);
}
__device__ __forceinline__ float bf2f(ushort u) {
  union { unsigned u; float f; } x; x.u = ((unsigned)u) << 16;
  return x.f;
}

__device__ __forceinline__ void gload_lds16(const void* g, void* l) {
  __builtin_amdgcn_global_load_lds(
      (const __attribute__((address_space(1))) void*)g,
      (__attribute__((address_space(3))) void*)l, 16, 0, 0);
}

// ---------------- fp32 -> bf16 convert, 3 tensors per launch ----------------
__global__ __launch_bounds__(256) void cvt3(
    const float4* __restrict__ s0, const float4* __restrict__ s1,
    const float4* __restrict__ s2, ushort4* __restrict__ d0,
    ushort4* __restrict__ d1, ushort4* __restrict__ d2, int n4) {
  int i = blockIdx.x * 256 + threadIdx.x;
  if (i >= n4) return;
  const float4* s = blockIdx.y == 0 ? s0 : (blockIdx.y == 1 ? s1 : s2);
  ushort4* d = blockIdx.y == 0 ? d0 : (blockIdx.y == 1 ? d1 : d2);
  float4 v = s[i];
  ushort4 o;
  o.x = f2bf(v.x); o.y = f2bf(v.y); o.z = f2bf(v.z); o.w = f2bf(v.w);
  d[i] = o;
}

// ========== 256x128 8-wave bf16 GEMM (B^T form), 2 blocks/CU ==========
// C[m,n] = f((sum_k A[m,k]*B[n,k])*(SCALED?scale:1) + bias), f=exp if EXPOUT
// BM=256, BN=128, BK=32. 8 waves (2m x 4n), per-wave 128x32 (acc[8][2]).
// 48KB LDS double-buffer, frag-major chunks (1KB = one wave-frag in lane order:
// conflict-free ds_read_b128; wave-uniform gload_lds dest). 2 blocks/CU:
// the co-resident block's MFMAs fill this block's barrier/LDS-burst stalls.
// Per K-tile: {10 ds_read | lgkm0 | bar | stage t+2 (3 gloads) | 16 MFMA |
//              vmcnt(3) | bar}  -- counted prefetch, no vmcnt(0) steady-state.
// Epilogue: C staged to LDS in 2x 32KB halves (XOR 32B-slot swizzle), coalesced
// flush. REDUCE: 0 none; 1 col max+sumexp partials; 2 col plain-sum partials.
template<int BIAS_MODE, int SCALED, int REDUCE, int EXPOUT>
__global__ __launch_bounds__(512, 4) void gemmP(
    const ushort* __restrict__ A, const ushort* __restrict__ B,
    ushort* __restrict__ Cv, const float* __restrict__ bias,
    float* __restrict__ red_max, float* __restrict__ red_sum,
    int N, int K, long sA, long sB, long sC, float scale, int gm, int gn)
{
  extern __shared__ ushort lds[];   // 49152 B: A [0,16K)x2 bufs, B 16K+[0,4K)x2

  // ---- tile decode: bijective XCD swizzle + banded order ----
  const int nwg = gridDim.x;
  const int wg = blockIdx.x;
  const int cpx = nwg >> 3;
  const int wid_ = (wg & 7) * cpx + (wg >> 3);
  const int tiles = gm * gn;
  const int bz = wid_ / tiles;
  const int t2 = wid_ - bz * tiles;
  const int band = t2 / (gm << 2);
  const int r2 = t2 - band * (gm << 2);
  const int tile_m = (r2 >> 2) * 256;
  const int tile_n = ((band << 2) + (r2 & 3)) * 128;

  const ushort* Ab = A + (size_t)bz * sA;
  const ushort* Bb = B + (size_t)bz * sB;
  const int t = threadIdx.x;
  const int lane = t & 63;
  const int w = t >> 6;
  const int wr = w >> 2;   // 0..1 (m half)
  const int wc = w & 3;    // 0..3 (n quarter, 32 cols)

  f32x4 acc[8][2] = {};

  // stage one K-tile: A 16 chunks (2/wave), B 8 chunks (1/wave)
#define STAGE(c, k0)                                                                   \
  do {                                                                                 \
    _Pragma("unroll") for (int o = 0; o < 2; ++o) {                                    \
      int cA = w + o * 8;                                                              \
      gload_lds16(Ab + (size_t)(tile_m + cA * 16 + (lane & 15)) * K + (k0) +           \
                      (lane >> 4) * 8,                                                 \
                  &lds[(c) * 8192 + cA * 512]);                                        \
    }                                                                                  \
    gload_lds16(Bb + (size_t)(tile_n + w * 16 + (lane & 15)) * K + (k0) +              \
                    (lane >> 4) * 8,                                                   \
                &lds[16384 + (c) * 4096 + w * 512]);                                   \
  } while (0)

  // ---- prologue ----
  STAGE(0, 0);
  STAGE(1, 32);
  asm volatile("s_waitcnt vmcnt(3)" ::: "memory");   // tile0 landed, tile1 in flight
  __builtin_amdgcn_s_barrier();

  const int KT = K >> 5;
  for (int tt = 0; tt < KT; ++tt) {
    const int c = tt & 1;
    bf16x8 aA[8], bB[2];
#pragma unroll
    for (int mi = 0; mi < 8; ++mi)
      aA[mi] = *(const bf16x8*)&lds[c * 8192 + (wr * 8 + mi) * 512 + lane * 8];
#pragma unroll
    for (int nf = 0; nf < 2; ++nf)
      bB[nf] = *(const bf16x8*)&lds[16384 + c * 4096 + (wc * 2 + nf) * 512 + lane * 8];
    asm volatile("s_waitcnt lgkmcnt(0)" ::: "memory");
    __builtin_amdgcn_sched_barrier(0);
    __builtin_amdgcn_s_barrier();                 // all waves done reading buf c
    if (tt + 2 < KT) STAGE(c, (tt + 2) << 5);     // overwrite c with tile t+2
    __builtin_amdgcn_s_setprio(1);
#pragma unroll
    for (int mi = 0; mi < 8; ++mi)
#pragma unroll
      for (int nf = 0; nf < 2; ++nf)
        acc[mi][nf] = __builtin_amdgcn_mfma_f32_16x16x32_bf16(aA[mi], bB[nf], acc[mi][nf], 0, 0, 0);
    __builtin_amdgcn_s_setprio(0);
    __builtin_amdgcn_sched_barrier(0);
    if (tt + 2 < KT)      asm volatile("s_waitcnt vmcnt(3)" ::: "memory"); // tile t+1 done
    else if (tt < KT - 1) asm volatile("s_waitcnt vmcnt(0)" ::: "memory"); // last prefetch
    __builtin_amdgcn_s_barrier();
  }
#undef STAGE

  // ---- epilogue: 2 half-tiles of 128x128 via LDS, coalesced flush ----
  float sm2[2] = {0.f, 0.f};
  const int g5 = ((lane >> 4) & 3) << 5;
  float bcn[2];
#pragma unroll
  for (int nf = 0; nf < 2; ++nf)
    bcn[nf] = (BIAS_MODE == 1) ? bias[tile_n + wc * 32 + nf * 16 + (lane & 15)] : 0.f;

#pragma unroll
  for (int h = 0; h < 2; ++h) {
    __syncthreads();
    if (wr == h) {
#pragma unroll
      for (int mi = 0; mi < 8; ++mi) {
#pragma unroll
        for (int j = 0; j < 4; ++j) {
          const int row = mi * 16 + ((lane >> 4) << 2) + j;   // 0..127
          float bcr = (BIAS_MODE == 2) ? bias[tile_m + h * 128 + row] : 0.f;
#pragma unroll
          for (int nf = 0; nf < 2; ++nf) {
            float val = acc[mi][nf][j];
            if (SCALED) val *= scale;
            if (BIAS_MODE == 1) val += bcn[nf];
            else if (BIAS_MODE == 2) val += bcr;
            if (EXPOUT) val = __expf(val);
            if (REDUCE == 2) sm2[nf] += val;
            int colb = (wc * 32 + nf * 16 + (lane & 15)) * 2;
            *(ushort*)((char*)lds + row * 256 + (colb ^ g5)) = f2bf(val);
          }
        }
      }
    }
    __syncthreads();
#pragma unroll
    for (int p = 0; p < 4; ++p) {
      int off = p * 8192 + t * 16;
      int row = off >> 8;
      int bcol = off & 255;
      int bs = bcol ^ (((row >> 2) & 3) << 5);
      float4 d = *(const float4*)((const char*)lds + row * 256 + bs);
      *(float4*)(Cv + (size_t)bz * sC + (size_t)(tile_m + h * 128 + row) * N +
                 tile_n + (bcol >> 1)) = d;
    }
  }

  if constexpr (REDUCE == 2) {   // plain column-sum partials (expS path)
    __syncthreads();
    float* sb = (float*)lds;     // [2][128]
#pragma unroll
    for (int nf = 0; nf < 2; ++nf) {
      float s1 = sm2[nf] + __shfl_xor(sm2[nf], 16);
      float Ss = s1 + __shfl_xor(s1, 32);
      if ((lane >> 4) == nf)
        sb[wr * 128 + wc * 32 + nf * 16 + (lane & 15)] = Ss;
    }
    __syncthreads();
    if (t < 128) {
      size_t rb = ((size_t)bz * gm + (tile_m >> 8)) * N + tile_n + t;
      red_sum[rb] = sb[t] + sb[128 + t];
    }
  }
  if constexpr (REDUCE == 1) {   // col max+sumexp partials (raw acc; PV path)
    __syncthreads();
    float* mb = (float*)lds;          // [2][128]
    float* sb = (float*)lds + 256;    // [2][128]
#pragma unroll
    for (int nf = 0; nf < 2; ++nf) {
      float mx = -1e30f;
#pragma unroll
      for (int mi = 0; mi < 8; ++mi)
#pragma unroll
        for (int j = 0; j < 4; ++j) mx = fmaxf(mx, acc[mi][nf][j]);
      float m1 = fmaxf(mx, __shfl_xor(mx, 16));
      float M = fmaxf(m1, __shfl_xor(m1, 32));
      float sm = 0.f;
#pragma unroll
      for (int mi = 0; mi < 8; ++mi)
#pragma unroll
        for (int j = 0; j < 4; ++j) sm += __expf(acc[mi][nf][j] - M);
      float s1 = sm + __shfl_xor(sm, 16);
      float Ss = s1 + __shfl_xor(s1, 32);
      if ((lane >> 4) == nf) {
        mb[wr * 128 + wc * 32 + nf * 16 + (lane & 15)] = M;
        sb[wr * 128 + wc * 32 + nf * 16 + (lane & 15)] = Ss;
      }
    }
    __syncthreads();
    if (t < 128) {
      float m0 = mb[t], m1v = mb[128 + t];
      float M = fmaxf(m0, m1v);
      float Ss = sb[t] * __expf(m0 - M) + sb[128 + t] * __expf(m1v - M);
      size_t rb = ((size_t)bz * gm + (tile_m >> 8)) * N + tile_n + t;
      red_max[rb] = M;
      red_sum[rb] = Ss;
    }
  }
}

// c[b,k] = 1 / sum_ch red_sum[b][ch][k]. grid: (cols/256, B)
__global__ __launch_bounds__(256) void combine_c(
    const float* __restrict__ red_sum, float* __restrict__ cvec, int cols, int nch)
{
  const int b = blockIdx.y;
  const int c = blockIdx.x * 256 + threadIdx.x;
  float Z = 0.f;
  for (int ch = 0; ch < nch; ++ch)
    Z += red_sum[((size_t)b * nch + ch) * cols + c];
  cvec[(size_t)b * cols + c] = 1.f / Z;
}

// vs[b][d][k] = vpT[b][d][k] * c[b][k]
__global__ __launch_bounds__(256) void scale_v(
    const ushort* __restrict__ vpT, const float* __restrict__ cvec,
    ushort* __restrict__ vs, int S, int DS)
{
  const size_t k8 = ((size_t)blockIdx.x * 256 + threadIdx.x) * 8;
  const int b = (int)(k8 / DS);
  const int kcol = (int)(k8 % S);
  ushort4 u0 = *(const ushort4*)(vpT + k8);
  ushort4 u1 = *(const ushort4*)(vpT + k8 + 4);
  const float* cb = cvec + (size_t)b * S + kcol;
  float4 c0 = *(const float4*)cb;
  float4 c1 = *(const float4*)(cb + 4);
  ushort4 o0, o1;
  o0.x = f2bf(bf2f(u0.x) * c0.x); o0.y = f2bf(bf2f(u0.y) * c0.y);
  o0.z = f2bf(bf2f(u0.z) * c0.z); o0.w = f2bf(bf2f(u0.w) * c0.w);
  o1.x = f2bf(bf2f(u1.x) * c1.x); o1.y = f2bf(bf2f(u1.y) * c1.y);
  o1.z = f2bf(bf2f(u1.z) * c1.z); o1.w = f2bf(bf2f(u1.w) * c1.w);
  *(ushort4*)(vs + k8) = o0;
  *(ushort4*)(vs + k8 + 4) = o1;
}

// combine partials -> M, 1/Z per (b,col). grid: (cols/256, B)
__global__ __launch_bounds__(256) void colsm_combine(
    const float* __restrict__ red_max, const float* __restrict__ red_sum,
    float* __restrict__ Mv, float* __restrict__ Zinv, int cols, int nch)
{
  const int b = blockIdx.y;
  const int c = blockIdx.x * 256 + threadIdx.x;
  float M = -1e30f, Z = 0.f;
  for (int ch = 0; ch < nch; ++ch) {
    size_t o = ((size_t)b * nch + ch) * cols + c;
    float m = red_max[o], s = red_sum[o];
    float nm = fmaxf(M, m);
    Z = Z * __expf(M - nm) + s * __expf(m - nm);
    M = nm;
  }
  Mv[(size_t)b * cols + c] = M;
  Zinv[(size_t)b * cols + c] = 1.f / Z;
}

// final: out1 = softmax(attn over rows), out0 = attn + residual. attn is bf16.
__global__ __launch_bounds__(256) void final_emit(
    const ushort* __restrict__ attnB, const float* __restrict__ q,
    float* __restrict__ out0, float* __restrict__ out1,
    const float* __restrict__ Mv, const float* __restrict__ Zinv,
    int rows, int cols, int rpc)
{
  const int b = blockIdx.y;
  const int ch = blockIdx.z;
  const size_t base = (size_t)b * rows * cols;
  const int c4 = (blockIdx.x * 256 + threadIdx.x) * 4;
  const int r0 = ch * rpc;
  float M[4], Zi[4];
#pragma unroll
  for (int i = 0; i < 4; ++i) {
    M[i] = Mv[(size_t)b * cols + c4 + i];
    Zi[i] = Zinv[(size_t)b * cols + c4 + i];
  }
  for (int r = r0; r < r0 + rpc; ++r) {
    size_t o = base + (size_t)r * cols + c4;
    ushort4 u = *(const ushort4*)(attnB + o);
    float4 qv = *(const float4*)(q + o);
    float a0 = bf2f(u.x), a1 = bf2f(u.y), a2 = bf2f(u.z), a3 = bf2f(u.w);
    float4 wv, s;
    wv.x = __expf(a0 - M[0]) * Zi[0];
    wv.y = __expf(a1 - M[1]) * Zi[1];
    wv.z = __expf(a2 - M[2]) * Zi[2];
    wv.w = __expf(a3 - M[3]) * Zi[3];
    s.x = a0 + qv.x; s.y = a1 + qv.y; s.z = a2 + qv.z; s.w = a3 + qv.w;
    *(float4*)(out1 + o) = wv;
    *(float4*)(out0 + o) = s;
  }
}

extern "C" void kernel_launch(void* const* d_in, const int* in_sizes, int n_in,
                              void* d_out, int out_size, void* d_ws, size_t ws_size,
                              hipStream_t stream) {
  const float* q  = (const float*)d_in[0];
  const float* k  = (const float*)d_in[1];
  const float* v  = (const float*)d_in[2];
  const float* Wq = (const float*)d_in[3];
  const float* bq = (const float*)d_in[4];
  const float* Wk = (const float*)d_in[5];
  const float* bk = (const float*)d_in[6];
  const float* Wv = (const float*)d_in[7];
  const float* bv = (const float*)d_in[8];
  float* out = (float*)d_out;

  const int B = 8, S = 2048, D = 1024;
  const long BS = (long)B * S;
  const long nQKV = BS * D;
  const long nW = (long)D * D;

  // d_out staging: qb/kb/vb bf16 [0,96M) (dead after vpT GEMM);
  // red_s_sum @96M (512KB), c_s @98M (64KB). final_emit overwrites d_out last.
  ushort* qb = (ushort*)d_out;
  ushort* kb = qb + nQKV;
  ushort* vb = kb + nQKV;
  float* red_s_sum = (float*)((char*)d_out + (96ull << 20));
  float* c_s       = (float*)((char*)d_out + (98ull << 20));

  // workspace map:
  //  [0,32M)  qp  -> (dead after scores)  vs
  //  [32,64M) kp  -> (dead after scores)  attnB
  //  [64,96M) vpT -> (dead after scale_v) red_f_max@64M, red_f_sum@65M, Mf@66M, Zf@67M
  //  [96,160M) Wqb/Wkb/Wvb (early) -> expS bf16 [b][q][k]
  char* ws = (char*)d_ws;
  ushort* qp     = (ushort*)ws;
  ushort* kp     = (ushort*)(ws + (32ull << 20));
  ushort* vpT    = (ushort*)(ws + (64ull << 20));
  ushort* Wqb    = (ushort*)(ws + (96ull << 20));
  ushort* Wkb    = Wqb + nW;
  ushort* Wvb    = Wkb + nW;
  ushort* expS   = (ushort*)(ws + (96ull << 20));
  ushort* vs     = (ushort*)ws;
  ushort* attnB  = (ushort*)(ws + (32ull << 20));
  float* red_f_max = (float*)(ws + (64ull << 20));
  float* red_f_sum = (float*)(ws + (65ull << 20));
  float* Mf        = (float*)(ws + (66ull << 20));
  float* Zf        = (float*)(ws + (67ull << 20));

  const int SH = 49152;
  (void)hipFuncSetAttribute(reinterpret_cast<const void*>(&gemmP<1,0,0,0>),
                            hipFuncAttributeMaxDynamicSharedMemorySize, SH);
  (void)hipFuncSetAttribute(reinterpret_cast<const void*>(&gemmP<2,0,0,0>),
                            hipFuncAttributeMaxDynamicSharedMemorySize, SH);
  (void)hipFuncSetAttribute(reinterpret_cast<const void*>(&gemmP<0,1,2,1>),
                            hipFuncAttributeMaxDynamicSharedMemorySize, SH);
  (void)hipFuncSetAttribute(reinterpret_cast<const void*>(&gemmP<0,0,1,0>),
                            hipFuncAttributeMaxDynamicSharedMemorySize, SH);

  // ---- conversions: 2 launches (weights; q/k/v) ----
  {
    int n4w = (int)(nW / 4);
    cvt3<<<dim3((n4w + 255) / 256, 3), 256, 0, stream>>>(
        (const float4*)Wq, (const float4*)Wk, (const float4*)Wv,
        (ushort4*)Wqb, (ushort4*)Wkb, (ushort4*)Wvb, n4w);
    int n4q = (int)(nQKV / 4);
    cvt3<<<dim3((n4q + 255) / 256, 3), 256, 0, stream>>>(
        (const float4*)q, (const float4*)k, (const float4*)v,
        (ushort4*)qb, (ushort4*)kb, (ushort4*)vb, n4q);
  }

  // qp[m][e] = q[m][:]·Wq[e][:] + bq[e]   (gm=64, gn=8, grid 512)
  gemmP<1,0,0,0><<<dim3(64 * 8), 512, SH, stream>>>(
      qb, Wqb, qp, bq, nullptr, nullptr, D, D, 0, 0, 0, 1.f, 64, 8);
  gemmP<1,0,0,0><<<dim3(64 * 8), 512, SH, stream>>>(
      kb, Wkb, kp, bk, nullptr, nullptr, D, D, 0, 0, 0, 1.f, 64, 8);
  // vpT[b][e][s] = Wv[e][:]·v[b][s][:] + bv[e]   (gm=4, gn=16, batch 8)
  gemmP<2,0,0,0><<<dim3(4 * 16 * B), 512, SH, stream>>>(
      Wvb, vb, vpT, bv, nullptr, nullptr, S, D, 0, (long)S * D, (long)D * S, 1.f, 4, 16);
  // expS = exp(qp·kp^T / 1024) + fused column-sum partials (gm=8, gn=16, batch 8)
  gemmP<0,1,2,1><<<dim3(8 * 16 * B), 512, SH, stream>>>(
      qp, kp, expS, nullptr, nullptr, red_s_sum,
      S, D, (long)S * D, (long)S * D, (long)S * S, 1.f / 1024.f, 8, 16);

  // c[b,k] = 1/colsum;  vs = vpT * c
  combine_c<<<dim3(S / 256, B), 256, 0, stream>>>(red_s_sum, c_s, S, 8);
  scale_v<<<dim3((int)(nQKV / (256 * 8))), 256, 0, stream>>>(vpT, c_s, vs, S, D * S);

  // attn = expS·vs^T (bf16) + fused final-softmax pass1 (gm=8, gn=8, batch 8)
  gemmP<0,0,1,0><<<dim3(8 * 8 * B), 512, SH, stream>>>(
      expS, vs, attnB, nullptr, red_f_max, red_f_sum,
      D, S, (long)S * S, (long)D * S, (long)S * D, 1.f, 8, 8);

  colsm_combine<<<dim3(D / 256, B), 256, 0, stream>>>(red_f_max, red_f_sum, Mf, Zf, D, 8);
  final_emit<<<dim3(1, B, 128), 256, 0, stream>>>(attnB, q, out, out + nQKV, Mf, Zf, S, D, 16);

  (void)in_sizes; (void)n_in; (void)out_size; (void)ws_size;
}

// Round 10
// 388.094 us; speedup vs baseline: 1.2257x; 1.2257x over previous
//
#include <hip/hip_runtime.h>

typedef __attribute__((ext_vector_type(8))) __bf16 bf16x8;
typedef __attribute__((ext_vector_type(4))) float f32x4;

__device__ __forceinline__ ushort f2bf(float f) {
  union { float f; unsigned u; } x; x.f = f;
  unsigned r = x.u + 0x7FFFu + ((x.u >> 16) & 1u);
  return (ushort)(r >> 16);
}
__device__ __forceinline__ float bf2f(ushort u) {
  union { unsigned u; float f; } x; x.u = ((unsigned)u) << 16;
  return x.f;
}

__device__ __forceinline__ void gload_lds16(const void* g, void* l) {
  __builtin_amdgcn_global_load_lds(
      (const __attribute__((address_space(1))) void*)g,
      (__attribute__((address_space(3))) void*)l, 16, 0, 0);
}

// ---------------- fp32 -> bf16 convert, 3 tensors per launch ----------------
__global__ __launch_bounds__(256) void cvt3(
    const float4* __restrict__ s0, const float4* __restrict__ s1,
    const float4* __restrict__ s2, ushort4* __restrict__ d0,
    ushort4* __restrict__ d1, ushort4* __restrict__ d2, int n4) {
  int i = blockIdx.x * 256 + threadIdx.x;
  if (i >= n4) return;
  const float4* s = blockIdx.y == 0 ? s0 : (blockIdx.y == 1 ? s1 : s2);
  ushort4* d = blockIdx.y == 0 ? d0 : (blockIdx.y == 1 ? d1 : d2);
  float4 v = s[i];
  ushort4 o;
  o.x = f2bf(v.x); o.y = f2bf(v.y); o.z = f2bf(v.z); o.w = f2bf(v.w);
  d[i] = o;
}

// ================= 256x256 8-wave 2-phase bf16 GEMM (B^T form) =================
// C[m,n] = f((sum_k A[m,k]*B[n,k])*(SCALED?scale:1) + bias), f=exp if EXPOUT
// 512 threads = 8 waves (2m x 4n), per-wave 128x64. BK=64, dbuf 128KiB LDS,
// frag-major chunks (1KB = one wave-frag in lane order; conflict-free
// ds_read_b128, linear gload_lds dest).
// TWO phases per K-tile (2 barriers, 2 vmcnt, 2 lgkm — publish-before-read
// invariant: every ds_read follows a barrier that follows all waves' vmcnt
// retiring that chunk's gload):
//  phA: WA vmcnt(2) [retire cur A0,B0,B1] | bar | stage A0',B0' | rd A0,B0,B1 (16)
//       | lgkm0 | 32 MFMA (m0-3 x n0-3)
//  phB: WB vmcnt(4) [retire cur A1]       | bar | stage B1',A1' | rd A1 (8, into
//       A-frag regs: A0 dead) | lgkm0 | 32 MFMA (m4-7 x n0-3)
// Per-wave gload issue order per tile: A0(2),B0(2),B1(2),A1(2).
// Steady ledger: entry out=8 (cur tile's 8); WA->2, +4 stage ->6; WB->4, +4 ->8.
// Last tile: WA=vmcnt(2), WB=vmcnt(0), no stage.
// Epilogue: C staged to LDS (bf16, 32B-slot XOR swizzle), coalesced flush.
// REDUCE: 0 none; 1 col max+sumexp partials; 2 col plain-sum partials.
template<int BIAS_MODE, int SCALED, int REDUCE, int EXPOUT>
__global__ __launch_bounds__(512, 2) void gemm256(
    const ushort* __restrict__ A, const ushort* __restrict__ B,
    ushort* __restrict__ Cv, const float* __restrict__ bias,
    float* __restrict__ red_max, float* __restrict__ red_sum,
    int N, int K, long sA, long sB, long sC, float scale, int gm, int gn)
{
  extern __shared__ ushort lds[];   // 131072 B

  // ---- tile decode: bijective XCD swizzle + banded order ----
  const int nwg = gridDim.x;
  const int wg = blockIdx.x;
  const int cpx = nwg >> 3;
  const int wid_ = (wg & 7) * cpx + (wg >> 3);
  const int tiles = gm * gn;
  const int bz = wid_ / tiles;
  const int t2 = wid_ - bz * tiles;
  const int band = t2 / (gm << 2);
  const int r2 = t2 - band * (gm << 2);
  const int tile_m = (r2 >> 2) * 256;
  const int tile_n = ((band << 2) + (r2 & 3)) * 256;

  const ushort* Ab = A + (size_t)bz * sA;
  const ushort* Bb = B + (size_t)bz * sB;
  const int t = threadIdx.x;
  const int lane = t & 63;
  const int w = t >> 6;
  const int wr = w >> 2;
  const int wc = w & 3;

  f32x4 acc[8][4] = {};
  bf16x8 aA[4][2], bB[4][2];

#define LDA(c, q)                                                                     \
  _Pragma("unroll") for (int mi = 0; mi < 4; ++mi)                                    \
  _Pragma("unroll") for (int kk = 0; kk < 2; ++kk)                                    \
    aA[mi][kk] = *(const bf16x8*)&lds[(c) * 16384 +                                   \
        ((wr * 8 + (q) * 4 + mi) * 2 + kk) * 512 + lane * 8];

#define LDB(c, h)                                                                     \
  _Pragma("unroll") for (int nf = 0; nf < 2; ++nf)                                    \
  _Pragma("unroll") for (int kk = 0; kk < 2; ++kk)                                    \
    bB[(h) * 2 + nf][kk] = *(const bf16x8*)&lds[32768 + (c) * 16384 +                 \
        ((wc * 4 + (h) * 2 + nf) * 2 + kk) * 512 + lane * 8];

#define STAGE_A(c, k0, q)                                                             \
  _Pragma("unroll") for (int o = 0; o < 2; ++o) {                                     \
    int g = w * 2 + o;                                                                \
    int rowblk = (g >> 3) * 8 + (q) * 4 + ((g >> 1) & 3);                             \
    int kk = g & 1;                                                                   \
    gload_lds16(Ab + (size_t)(tile_m + rowblk * 16 + (lane & 15)) * K +               \
                    (k0) + kk * 32 + (lane >> 4) * 8,                                 \
                &lds[(c) * 16384 + (rowblk * 2 + kk) * 512]);                         \
  }

#define STAGE_B(c, k0, q)                                                             \
  _Pragma("unroll") for (int o = 0; o < 2; ++o) {                                     \
    int g = w * 2 + o;                                                                \
    int rowblk = (g >> 2) * 4 + (q) * 2 + ((g >> 1) & 1);                             \
    int kk = g & 1;                                                                   \
    gload_lds16(Bb + (size_t)(tile_n + rowblk * 16 + (lane & 15)) * K +               \
                    (k0) + kk * 32 + (lane >> 4) * 8,                                 \
                &lds[32768 + (c) * 16384 + (rowblk * 2 + kk) * 512]);                 \
  }

#define MFMA_PH(MB, NB)                                                               \
  _Pragma("unroll") for (int kk = 0; kk < 2; ++kk)                                    \
  _Pragma("unroll") for (int mi = 0; mi < 4; ++mi)                                    \
  _Pragma("unroll") for (int nf = 0; nf < 2; ++nf)                                    \
    acc[(MB) + mi][(NB) + nf] = __builtin_amdgcn_mfma_f32_16x16x32_bf16(              \
        aA[mi][kk], bB[(NB) + nf][kk], acc[(MB) + mi][(NB) + nf], 0, 0, 0);

#define ITER2(c, DOSTAGE, k0n, WA, WB)                                                \
  {                                                                                   \
    /* ---- phase A: m0-3 x n0-3 ---- */                                              \
    asm volatile(WA ::: "memory");                                                    \
    __builtin_amdgcn_s_barrier();                                                     \
    if (DOSTAGE) { STAGE_A((c) ^ 1, k0n, 0); STAGE_B((c) ^ 1, k0n, 0); }              \
    LDA(c, 0);                                                                        \
    LDB(c, 0);                                                                        \
    LDB(c, 1);                                                                        \
    asm volatile("s_waitcnt lgkmcnt(0)" ::: "memory");                                \
    __builtin_amdgcn_sched_barrier(0);                                                \
    __builtin_amdgcn_s_setprio(1);                                                    \
    MFMA_PH(0, 0);                                                                    \
    MFMA_PH(0, 2);                                                                    \
    __builtin_amdgcn_s_setprio(0);                                                    \
    /* ---- phase B: m4-7 x n0-3 ---- */                                              \
    asm volatile(WB ::: "memory");                                                    \
    __builtin_amdgcn_s_barrier();                                                     \
    if (DOSTAGE) { STAGE_B((c) ^ 1, k0n, 1); STAGE_A((c) ^ 1, k0n, 1); }              \
    LDA(c, 1);                                                                        \
    asm volatile("s_waitcnt lgkmcnt(0)" ::: "memory");                                \
    __builtin_amdgcn_sched_barrier(0);                                                \
    __builtin_amdgcn_s_setprio(1);                                                    \
    MFMA_PH(4, 0);                                                                    \
    MFMA_PH(4, 2);                                                                    \
    __builtin_amdgcn_s_setprio(0);                                                    \
  }

  // ---- prologue: stage K-tile 0 into buf 0, issue order A0,B0,B1,A1 ----
  STAGE_A(0, 0, 0);
  STAGE_B(0, 0, 0);
  STAGE_B(0, 0, 1);
  STAGE_A(0, 0, 1);

  const int KT = K >> 6;
  for (int tt = 0; tt < KT - 1; ++tt) {
    const int c = tt & 1;
    const int k0n = (tt + 1) << 6;
    ITER2(c, true, k0n, "s_waitcnt vmcnt(2)", "s_waitcnt vmcnt(4)");
  }
  // peeled last K-tile: no staging
  ITER2(((KT - 1) & 1), false, 0, "s_waitcnt vmcnt(2)", "s_waitcnt vmcnt(0)");

#undef ITER2
#undef MFMA_PH
#undef STAGE_A
#undef STAGE_B
#undef LDA
#undef LDB

  __builtin_amdgcn_s_barrier();   // all MFMA/ds reads done before epilogue LDS reuse

  // ---- epilogue: stage C tile into LDS (bf16, XOR-swizzled 32B slots) ----
  float sm2[4] = {0.f, 0.f, 0.f, 0.f};   // REDUCE==2 column sums
  {
    float bcn[4]; int ccl[4];
#pragma unroll
    for (int nf = 0; nf < 4; ++nf) {
      ccl[nf] = wc * 64 + nf * 16 + (lane & 15);
      bcn[nf] = (BIAS_MODE == 1) ? bias[tile_n + ccl[nf]] : 0.f;
    }
    const int g5 = ((lane >> 4) & 3) << 5;
#pragma unroll
    for (int mi = 0; mi < 8; ++mi) {
#pragma unroll
      for (int j = 0; j < 4; ++j) {
        const int row = wr * 128 + mi * 16 + ((lane >> 4) << 2) + j;
        float bcr = (BIAS_MODE == 2) ? bias[tile_m + row] : 0.f;
#pragma unroll
        for (int nf = 0; nf < 4; ++nf) {
          float val = acc[mi][nf][j];
          if (SCALED) val *= scale;
          if (BIAS_MODE == 1) val += bcn[nf];
          else if (BIAS_MODE == 2) val += bcr;
          if (EXPOUT) val = __expf(val);
          if (REDUCE == 2) sm2[nf] += val;
          *(ushort*)((char*)lds + row * 512 + ((ccl[nf] * 2) ^ g5)) = f2bf(val);
        }
      }
    }
  }
  __syncthreads();
  // ---- coalesced flush: 16 passes x 512 threads x 16B ----
#pragma unroll
  for (int p = 0; p < 16; ++p) {
    int off = p * 8192 + t * 16;
    int row = off >> 9;
    int b = off & 511;
    int bs = b ^ (((row >> 2) & 3) << 5);
    float4 d = *(const float4*)((const char*)lds + row * 512 + bs);
    *(float4*)(Cv + (size_t)bz * sC + (size_t)(tile_m + row) * N + tile_n + (b >> 1)) = d;
  }

  if constexpr (REDUCE == 2) {   // plain column-sum partials (expS path)
    __syncthreads();
    float* sb = (float*)lds;     // [2][256]
#pragma unroll
    for (int nf = 0; nf < 4; ++nf) {
      float s1 = sm2[nf] + __shfl_xor(sm2[nf], 16);
      float Ss = s1 + __shfl_xor(s1, 32);
      if ((lane >> 4) == nf)
        sb[wr * 256 + wc * 64 + nf * 16 + (lane & 15)] = Ss;
    }
    __syncthreads();
    if (t < 256) {
      size_t rb = ((size_t)bz * gm + (tile_m >> 8)) * N + tile_n + t;
      red_sum[rb] = sb[t] + sb[256 + t];
    }
  }
  if constexpr (REDUCE == 1) {   // col max+sumexp partials (raw acc; PV path)
    __syncthreads();
    float* mb = (float*)lds;          // [2][256]
    float* sb = (float*)lds + 512;    // [2][256]
#pragma unroll
    for (int nf = 0; nf < 4; ++nf) {
      const int cl = wc * 64 + nf * 16 + (lane & 15);
      float mx = -1e30f;
#pragma unroll
      for (int mi = 0; mi < 8; ++mi)
#pragma unroll
        for (int j = 0; j < 4; ++j) mx = fmaxf(mx, acc[mi][nf][j]);
      float m1 = fmaxf(mx, __shfl_xor(mx, 16));
      float M = fmaxf(m1, __shfl_xor(m1, 32));
      float sm = 0.f;
#pragma unroll
      for (int mi = 0; mi < 8; ++mi)
#pragma unroll
        for (int j = 0; j < 4; ++j) sm += __expf(acc[mi][nf][j] - M);
      float s1 = sm + __shfl_xor(sm, 16);
      float Ss = s1 + __shfl_xor(s1, 32);
      if ((lane >> 4) == nf) {
        mb[wr * 256 + cl] = M;
        sb[wr * 256 + cl] = Ss;
      }
    }
    __syncthreads();
    if (t < 256) {
      float m0 = mb[t], m1v = mb[256 + t];
      float M = fmaxf(m0, m1v);
      float Ss = sb[t] * __expf(m0 - M) + sb[256 + t] * __expf(m1v - M);
      size_t rb = ((size_t)bz * gm + (tile_m >> 8)) * N + tile_n + t;
      red_max[rb] = M;
      red_sum[rb] = Ss;
    }
  }
}

// c[b,k] = 1 / sum_ch red_sum[b][ch][k]. grid: (cols/256, B)
__global__ __launch_bounds__(256) void combine_c(
    const float* __restrict__ red_sum, float* __restrict__ cvec, int cols, int nch)
{
  const int b = blockIdx.y;
  const int c = blockIdx.x * 256 + threadIdx.x;
  float Z = 0.f;
  for (int ch = 0; ch < nch; ++ch)
    Z += red_sum[((size_t)b * nch + ch) * cols + c];
  cvec[(size_t)b * cols + c] = 1.f / Z;
}

// vs[b][d][k] = vpT[b][d][k] * c[b][k]
__global__ __launch_bounds__(256) void scale_v(
    const ushort* __restrict__ vpT, const float* __restrict__ cvec,
    ushort* __restrict__ vs, int S, int DS)
{
  const size_t k8 = ((size_t)blockIdx.x * 256 + threadIdx.x) * 8;
  const int b = (int)(k8 / DS);
  const int kcol = (int)(k8 % S);
  ushort4 u0 = *(const ushort4*)(vpT + k8);
  ushort4 u1 = *(const ushort4*)(vpT + k8 + 4);
  const float* cb = cvec + (size_t)b * S + kcol;
  float4 c0 = *(const float4*)cb;
  float4 c1 = *(const float4*)(cb + 4);
  ushort4 o0, o1;
  o0.x = f2bf(bf2f(u0.x) * c0.x); o0.y = f2bf(bf2f(u0.y) * c0.y);
  o0.z = f2bf(bf2f(u0.z) * c0.z); o0.w = f2bf(bf2f(u0.w) * c0.w);
  o1.x = f2bf(bf2f(u1.x) * c1.x); o1.y = f2bf(bf2f(u1.y) * c1.y);
  o1.z = f2bf(bf2f(u1.z) * c1.z); o1.w = f2bf(bf2f(u1.w) * c1.w);
  *(ushort4*)(vs + k8) = o0;
  *(ushort4*)(vs + k8 + 4) = o1;
}

// combine partials -> M, 1/Z per (b,col). grid: (cols/256, B)
__global__ __launch_bounds__(256) void colsm_combine(
    const float* __restrict__ red_max, const float* __restrict__ red_sum,
    float* __restrict__ Mv, float* __restrict__ Zinv, int cols, int nch)
{
  const int b = blockIdx.y;
  const int c = blockIdx.x * 256 + threadIdx.x;
  float M = -1e30f, Z = 0.f;
  for (int ch = 0; ch < nch; ++ch) {
    size_t o = ((size_t)b * nch + ch) * cols + c;
    float m = red_max[o], s = red_sum[o];
    float nm = fmaxf(M, m);
    Z = Z * __expf(M - nm) + s * __expf(m - nm);
    M = nm;
  }
  Mv[(size_t)b * cols + c] = M;
  Zinv[(size_t)b * cols + c] = 1.f / Z;
}

// final: out1 = softmax(attn over rows), out0 = attn + residual. attn is bf16.
__global__ __launch_bounds__(256) void final_emit(
    const ushort* __restrict__ attnB, const float* __restrict__ q,
    float* __restrict__ out0, float* __restrict__ out1,
    const float* __restrict__ Mv, const float* __restrict__ Zinv,
    int rows, int cols, int rpc)
{
  const int b = blockIdx.y;
  const int ch = blockIdx.z;
  const size_t base = (size_t)b * rows * cols;
  const int c4 = (blockIdx.x * 256 + threadIdx.x) * 4;
  const int r0 = ch * rpc;
  float M[4], Zi[4];
#pragma unroll
  for (int i = 0; i < 4; ++i) {
    M[i] = Mv[(size_t)b * cols + c4 + i];
    Zi[i] = Zinv[(size_t)b * cols + c4 + i];
  }
  for (int r = r0; r < r0 + rpc; ++r) {
    size_t o = base + (size_t)r * cols + c4;
    ushort4 u = *(const ushort4*)(attnB + o);
    float4 qv = *(const float4*)(q + o);
    float a0 = bf2f(u.x), a1 = bf2f(u.y), a2 = bf2f(u.z), a3 = bf2f(u.w);
    float4 wv, s;
    wv.x = __expf(a0 - M[0]) * Zi[0];
    wv.y = __expf(a1 - M[1]) * Zi[1];
    wv.z = __expf(a2 - M[2]) * Zi[2];
    wv.w = __expf(a3 - M[3]) * Zi[3];
    s.x = a0 + qv.x; s.y = a1 + qv.y; s.z = a2 + qv.z; s.w = a3 + qv.w;
    *(float4*)(out1 + o) = wv;
    *(float4*)(out0 + o) = s;
  }
}

extern "C" void kernel_launch(void* const* d_in, const int* in_sizes, int n_in,
                              void* d_out, int out_size, void* d_ws, size_t ws_size,
                              hipStream_t stream) {
  const float* q  = (const float*)d_in[0];
  const float* k  = (const float*)d_in[1];
  const float* v  = (const float*)d_in[2];
  const float* Wq = (const float*)d_in[3];
  const float* bq = (const float*)d_in[4];
  const float* Wk = (const float*)d_in[5];
  const float* bk = (const float*)d_in[6];
  const float* Wv = (const float*)d_in[7];
  const float* bv = (const float*)d_in[8];
  float* out = (float*)d_out;

  const int B = 8, S = 2048, D = 1024;
  const long BS = (long)B * S;
  const long nQKV = BS * D;
  const long nW = (long)D * D;

  // d_out staging: qb/kb/vb bf16 [0,96M) (dead after vpT GEMM);
  // red_s_sum @96M (512KB), c_s @98M (64KB). final_emit overwrites d_out last.
  ushort* qb = (ushort*)d_out;
  ushort* kb = qb + nQKV;
  ushort* vb = kb + nQKV;
  float* red_s_sum = (float*)((char*)d_out + (96ull << 20));
  float* c_s       = (float*)((char*)d_out + (98ull << 20));

  // workspace map:
  //  [0,32M)  qp  -> (dead after scores)  vs
  //  [32,64M) kp  -> (dead after scores)  attnB
  //  [64,96M) vpT -> (dead after scale_v) red_f_max@64M, red_f_sum@65M, Mf@66M, Zf@67M
  //  [96,160M) Wqb/Wkb/Wvb (early) -> expS bf16 [b][q][k]
  char* ws = (char*)d_ws;
  ushort* qp     = (ushort*)ws;
  ushort* kp     = (ushort*)(ws + (32ull << 20));
  ushort* vpT    = (ushort*)(ws + (64ull << 20));
  ushort* Wqb    = (ushort*)(ws + (96ull << 20));
  ushort* Wkb    = Wqb + nW;
  ushort* Wvb    = Wkb + nW;
  ushort* expS   = (ushort*)(ws + (96ull << 20));
  ushort* vs     = (ushort*)ws;
  ushort* attnB  = (ushort*)(ws + (32ull << 20));
  float* red_f_max = (float*)(ws + (64ull << 20));
  float* red_f_sum = (float*)(ws + (65ull << 20));
  float* Mf        = (float*)(ws + (66ull << 20));
  float* Zf        = (float*)(ws + (67ull << 20));

  const int SH = 131072;
  (void)hipFuncSetAttribute(reinterpret_cast<const void*>(&gemm256<1,0,0,0>),
                            hipFuncAttributeMaxDynamicSharedMemorySize, SH);
  (void)hipFuncSetAttribute(reinterpret_cast<const void*>(&gemm256<2,0,0,0>),
                            hipFuncAttributeMaxDynamicSharedMemorySize, SH);
  (void)hipFuncSetAttribute(reinterpret_cast<const void*>(&gemm256<0,1,2,1>),
                            hipFuncAttributeMaxDynamicSharedMemorySize, SH);
  (void)hipFuncSetAttribute(reinterpret_cast<const void*>(&gemm256<0,0,1,0>),
                            hipFuncAttributeMaxDynamicSharedMemorySize, SH);

  // ---- conversions: 2 launches (weights; q/k/v) ----
  {
    int n4w = (int)(nW / 4);
    cvt3<<<dim3((n4w + 255) / 256, 3), 256, 0, stream>>>(
        (const float4*)Wq, (const float4*)Wk, (const float4*)Wv,
        (ushort4*)Wqb, (ushort4*)Wkb, (ushort4*)Wvb, n4w);
    int n4q = (int)(nQKV / 4);
    cvt3<<<dim3((n4q + 255) / 256, 3), 256, 0, stream>>>(
        (const float4*)q, (const float4*)k, (const float4*)v,
        (ushort4*)qb, (ushort4*)kb, (ushort4*)vb, n4q);
  }

  // qp[m][e] = q[m][:]·Wq[e][:] + bq[e]   (gm=64, gn=4)
  gemm256<1,0,0,0><<<dim3(64 * 4), 512, SH, stream>>>(
      qb, Wqb, qp, bq, nullptr, nullptr, D, D, 0, 0, 0, 1.f, 64, 4);
  gemm256<1,0,0,0><<<dim3(64 * 4), 512, SH, stream>>>(
      kb, Wkb, kp, bk, nullptr, nullptr, D, D, 0, 0, 0, 1.f, 64, 4);
  // vpT[b][e][s] = Wv[e][:]·v[b][s][:] + bv[e]   (gm=4, gn=8, batch 8)
  gemm256<2,0,0,0><<<dim3(4 * 8 * B), 512, SH, stream>>>(
      Wvb, vb, vpT, bv, nullptr, nullptr, S, D, 0, (long)S * D, (long)D * S, 1.f, 4, 8);
  // expS = exp(qp·kp^T / 1024) + fused column-sum partials   (gm=8, gn=8, batch 8)
  gemm256<0,1,2,1><<<dim3(8 * 8 * B), 512, SH, stream>>>(
      qp, kp, expS, nullptr, nullptr, red_s_sum,
      S, D, (long)S * D, (long)S * D, (long)S * S, 1.f / 1024.f, 8, 8);

  // c[b,k] = 1/colsum;  vs = vpT * c
  combine_c<<<dim3(S / 256, B), 256, 0, stream>>>(red_s_sum, c_s, S, 8);
  scale_v<<<dim3((int)(nQKV / (256 * 8))), 256, 0, stream>>>(vpT, c_s, vs, S, D * S);

  // attn = expS·vs^T (bf16) + fused final-softmax pass1   (gm=8, gn=4, batch 8)
  gemm256<0,0,1,0><<<dim3(8 * 4 * B), 512, SH, stream>>>(
      expS, vs, attnB, nullptr, red_f_max, red_f_sum,
      D, S, (long)S * S, (long)D * S, (long)S * D, 1.f, 8, 4);

  colsm_combine<<<dim3(D / 256, B), 256, 0, stream>>>(red_f_max, red_f_sum, Mf, Zf, D, 8);
  final_emit<<<dim3(1, B, 128), 256, 0, stream>>>(attnB, q, out, out + nQKV, Mf, Zf, S, D, 16);

  (void)in_sizes; (void)n_in; (void)out_size; (void)ws_size;
}